// Round 7
// baseline (210.967 us; speedup 1.0000x reference)
//
#include <hip/hip_runtime.h>
#include <hip/hip_bf16.h>

#define NROWS 8192
#define DIM 512
#define BM 128
#define BN 128
#define BK 64
#define NTILES (NROWS / BM)   // 64

using short8 = __attribute__((ext_vector_type(8))) short;
using f32x4  = __attribute__((ext_vector_type(4))) float;

static __device__ __forceinline__ unsigned short f2bf(float f) {
    unsigned int u = __float_as_uint(f);
    u += 0x7fffu + ((u >> 16) & 1u);   // RNE
    return (unsigned short)(u >> 16);
}

#define GLD_TO_LDS16(gsrc, ldst)                                                   \
    __builtin_amdgcn_global_load_lds(                                              \
        (const __attribute__((address_space(1))) void*)(gsrc),                     \
        (__attribute__((address_space(3))) void*)(ldst), 16, 0, 0)

// ---------------- Kernel 1: L2-normalize rows, fp32 -> bf16 ----------------
__global__ __launch_bounds__(256) void normalize_kernel(
        const float* __restrict__ embs, unsigned short* __restrict__ e) {
    const int row = blockIdx.x;
    const int tid = threadIdx.x;
    const float2 v = reinterpret_cast<const float2*>(embs + (size_t)row * DIM)[tid];
    float ss = v.x * v.x + v.y * v.y;
    #pragma unroll
    for (int off = 32; off; off >>= 1) ss += __shfl_xor(ss, off);
    __shared__ float s[4];
    if ((tid & 63) == 0) s[tid >> 6] = ss;
    __syncthreads();
    const float tot = s[0] + s[1] + s[2] + s[3];
    const float rn = rsqrtf(tot);
    ushort2 o;
    o.x = f2bf(v.x * rn);
    o.y = f2bf(v.y * rn);
    reinterpret_cast<ushort2*>(e + (size_t)row * DIM)[tid] = o;
}

// ---------------- Kernel 2: fused sim GEMM + exp + masked row sums ----------------
// Block (bx, by): cols [bx*128, +128), rows [by*128, +128).
// Writes exclusive slice part_tot[bx][rows], part_pos[bx][rows] -> no atomics on global.
__global__ __launch_bounds__(256) void sim_kernel(
        const unsigned short* __restrict__ e, const int* __restrict__ labels,
        float* __restrict__ part_tot, float* __restrict__ part_pos) {
    __shared__ __align__(128) unsigned short sA[BM][BK];
    __shared__ __align__(128) unsigned short sB[BN][BK];
    __shared__ float s_tot[BM], s_pos[BM];
    __shared__ int s_labA[BM], s_labB[BN];

    const int tid  = threadIdx.x;
    const int lane = tid & 63;
    const int wv   = tid >> 6;
    const int wr   = wv >> 1;           // wave row in 2x2 grid
    const int wc   = wv & 1;            // wave col
    const int lo   = lane & 15;
    const int hi   = lane >> 4;

    const int c0 = blockIdx.x * BN;
    const int r0 = blockIdx.y * BM;

    if (tid < BM) {
        s_tot[tid] = 0.f;
        s_pos[tid] = 0.f;
        s_labA[tid] = labels[r0 + tid];
        s_labB[tid] = labels[c0 + tid];
    }

    f32x4 acc[4][4];
    #pragma unroll
    for (int m = 0; m < 4; ++m)
        #pragma unroll
        for (int n = 0; n < 4; ++n)
            acc[m][n] = f32x4{0.f, 0.f, 0.f, 0.f};

    for (int kt = 0; kt < DIM / BK; ++kt) {
        __syncthreads();   // LDS reuse safety + (kt==0) init visibility
        const int k0 = kt * BK;
        #pragma unroll
        for (int it = 0; it < 4; ++it) {
            const int t_lin = it * 256 + tid;          // 0..1023 chunk id (16B chunks)
            const int r   = t_lin >> 3;                // row 0..127
            const int cc8 = (t_lin & 7) * 8;           // col element 0,8,..,56
            const unsigned short* srcA = e + (size_t)(r0 + r) * DIM + k0 + cc8;
            const unsigned short* srcB = e + (size_t)(c0 + r) * DIM + k0 + cc8;
            GLD_TO_LDS16(srcA, &sA[r][cc8]);
            GLD_TO_LDS16(srcB, &sB[r][cc8]);
        }
        __syncthreads();   // compiler drains vmcnt before the barrier

        #pragma unroll
        for (int ks = 0; ks < BK / 32; ++ks) {
            const int kb = ks * 32 + hi * 8;
            short8 a[4], b[4];
            #pragma unroll
            for (int m = 0; m < 4; ++m)
                a[m] = *reinterpret_cast<const short8*>(&sA[wr * 64 + m * 16 + lo][kb]);
            #pragma unroll
            for (int n = 0; n < 4; ++n)
                b[n] = *reinterpret_cast<const short8*>(&sB[wc * 64 + n * 16 + lo][kb]);
            #pragma unroll
            for (int m = 0; m < 4; ++m)
                #pragma unroll
                for (int n = 0; n < 4; ++n)
                    acc[m][n] = __builtin_amdgcn_mfma_f32_16x16x32_bf16(a[m], b[n], acc[m][n], 0, 0, 0);
        }
    }

    // ---------------- epilogue: exp + masks + per-row sums ----------------
    // C/D layout (m89-verified): col = n*16 + lo, row = m*16 + hi*4 + r
    #pragma unroll
    for (int m = 0; m < 4; ++m) {
        #pragma unroll
        for (int r = 0; r < 4; ++r) {
            const int lrow = wr * 64 + m * 16 + hi * 4 + r;
            const int grow = r0 + lrow;
            const int labr = s_labA[lrow];
            float tp = 0.f, pp = 0.f;
            #pragma unroll
            for (int n = 0; n < 4; ++n) {
                const int lcol = wc * 64 + n * 16 + lo;
                const int gcol = c0 + lcol;
                const float v = __expf(acc[m][n][r]);   // tau = 1
                const float vt = (grow == gcol) ? 0.f : v;
                tp += vt;
                pp += (s_labB[lcol] == labr) ? vt : 0.f;
            }
            #pragma unroll
            for (int off = 1; off <= 8; off <<= 1) {
                tp += __shfl_xor(tp, off);
                pp += __shfl_xor(pp, off);
            }
            if (lo == 0) {
                atomicAdd(&s_tot[lrow], tp);   // LDS atomics (ds_add_f32)
                atomicAdd(&s_pos[lrow], pp);
            }
        }
    }
    __syncthreads();
    if (tid < BM) {
        part_tot[(size_t)blockIdx.x * NROWS + r0 + tid] = s_tot[tid];
        part_pos[(size_t)blockIdx.x * NROWS + r0 + tid] = s_pos[tid];
    }
}

// ---------------- Kernel 3: per-row loss, per-block partial reduce ----------------
__global__ __launch_bounds__(256) void rowloss_kernel(
        const float* __restrict__ part_tot, const float* __restrict__ part_pos,
        float* __restrict__ blk_sum, float* __restrict__ blk_cnt) {
    const int tid = threadIdx.x;
    const int row = blockIdx.x * 256 + tid;
    float t = 0.f, p = 0.f;
    for (int c = 0; c < NTILES; ++c) {
        t += part_tot[(size_t)c * NROWS + row];
        p += part_pos[(size_t)c * NROWS + row];
    }
    float li = 0.f, vc = 0.f;
    if (p > 0.f) { li = logf(t) - logf(p); vc = 1.f; }
    #pragma unroll
    for (int off = 32; off; off >>= 1) {
        li += __shfl_xor(li, off);
        vc += __shfl_xor(vc, off);
    }
    __shared__ float ss[4], sc[4];
    if ((tid & 63) == 0) { ss[tid >> 6] = li; sc[tid >> 6] = vc; }
    __syncthreads();
    if (tid == 0) {
        blk_sum[blockIdx.x] = ss[0] + ss[1] + ss[2] + ss[3];
        blk_cnt[blockIdx.x] = sc[0] + sc[1] + sc[2] + sc[3];
    }
}

__global__ void final_kernel(const float* __restrict__ blk_sum,
                             const float* __restrict__ blk_cnt,
                             float* __restrict__ out) {
    float s = 0.f, c = 0.f;
    for (int i = 0; i < NROWS / 256; ++i) { s += blk_sum[i]; c += blk_cnt[i]; }
    out[0] = (c > 0.f) ? s / c : 0.f;
}

// ---------------- host ----------------
extern "C" void kernel_launch(void* const* d_in, const int* in_sizes, int n_in,
                              void* d_out, int out_size, void* d_ws, size_t ws_size,
                              hipStream_t stream) {
    const float* embs  = (const float*)d_in[0];
    const int* labels  = (const int*)d_in[1];
    float* out         = (float*)d_out;

    // workspace layout
    unsigned short* e = (unsigned short*)d_ws;                       // 8 MB bf16 normalized
    size_t off = (size_t)NROWS * DIM * sizeof(unsigned short);       // 8388608
    float* part_tot = (float*)((char*)d_ws + off);  off += (size_t)NTILES * NROWS * sizeof(float);
    float* part_pos = (float*)((char*)d_ws + off);  off += (size_t)NTILES * NROWS * sizeof(float);
    float* blk_sum  = (float*)((char*)d_ws + off);  off += 64 * sizeof(float);
    float* blk_cnt  = (float*)((char*)d_ws + off);

    normalize_kernel<<<NROWS, 256, 0, stream>>>(embs, e);
    sim_kernel<<<dim3(NTILES, NTILES), 256, 0, stream>>>(e, labels, part_tot, part_pos);
    rowloss_kernel<<<NROWS / 256, 256, 0, stream>>>(part_tot, part_pos, blk_sum, blk_cnt);
    final_kernel<<<1, 1, 0, stream>>>(blk_sum, blk_cnt, out);
}

// Round 8
// 186.801 us; speedup vs baseline: 1.1294x; 1.1294x over previous
//
#include <hip/hip_runtime.h>
#include <hip/hip_bf16.h>

#define NROWS 8192
#define DIM 512
#define BM 128
#define BN 128
#define BK 64
#define NTILES (NROWS / BM)   // 64

using short8 = __attribute__((ext_vector_type(8))) short;
using f32x4  = __attribute__((ext_vector_type(4))) float;

static __device__ __forceinline__ unsigned short f2bf(float f) {
    unsigned int u = __float_as_uint(f);
    u += 0x7fffu + ((u >> 16) & 1u);   // RNE
    return (unsigned short)(u >> 16);
}

#define GLD_TO_LDS16(gsrc, ldst)                                                   \
    __builtin_amdgcn_global_load_lds(                                              \
        (const __attribute__((address_space(1))) void*)(gsrc),                     \
        (__attribute__((address_space(3))) void*)(ldst), 16, 0, 0)

// ---------------- Kernel 1: L2-normalize rows, fp32 -> bf16 ----------------
__global__ __launch_bounds__(256) void normalize_kernel(
        const float* __restrict__ embs, unsigned short* __restrict__ e) {
    const int row = blockIdx.x;
    const int tid = threadIdx.x;
    const float2 v = reinterpret_cast<const float2*>(embs + (size_t)row * DIM)[tid];
    float ss = v.x * v.x + v.y * v.y;
    #pragma unroll
    for (int off = 32; off; off >>= 1) ss += __shfl_xor(ss, off);
    __shared__ float s[4];
    if ((tid & 63) == 0) s[tid >> 6] = ss;
    __syncthreads();
    const float tot = s[0] + s[1] + s[2] + s[3];
    const float rn = rsqrtf(tot);
    ushort2 o;
    o.x = f2bf(v.x * rn);
    o.y = f2bf(v.y * rn);
    reinterpret_cast<ushort2*>(e + (size_t)row * DIM)[tid] = o;
}

// ---------------- Kernel 2: fused sim GEMM + exp + masked row/col sums --------
// Symmetry: S = S^T. Only blocks with bx >= by compute. Block (bx,by):
//   rows r0 = by*128 (A-strip), cols c0 = bx*128 (B-strip).
//   Row-sums  -> part[bx][r0 .. r0+127]   (exclusive: (bx,by) unique for s>=t)
//   Col-sums  -> part[by][c0 .. c0+127]   (mirror block's row-sums; bx!=by only)
// Every (slice, row-tile) slot is written exactly once per launch -> no global
// atomics, safe under 0xAA ws re-poison.
__global__ __launch_bounds__(256) void sim_kernel(
        const unsigned short* __restrict__ e, const int* __restrict__ labels,
        float* __restrict__ part_tot, float* __restrict__ part_pos) {
    const int bx = blockIdx.x;
    const int by = blockIdx.y;
    if (bx < by) return;                 // lower triangle: mirror handled by (by,bx)
    const bool diag = (bx == by);

    __shared__ __align__(128) unsigned short sA[BM][BK];
    __shared__ __align__(128) unsigned short sB[BN][BK];
    __shared__ float s_tot[BM], s_pos[BM];
    __shared__ float s_ctot[BN], s_cpos[BN];
    __shared__ int s_labA[BM], s_labB[BN];

    const int tid  = threadIdx.x;
    const int lane = tid & 63;
    const int wv   = tid >> 6;
    const int wr   = wv >> 1;           // wave row in 2x2 grid
    const int wc   = wv & 1;            // wave col
    const int lo   = lane & 15;
    const int hi   = lane >> 4;

    const int c0 = bx * BN;
    const int r0 = by * BM;

    if (tid < BM) {
        s_tot[tid] = 0.f;
        s_pos[tid] = 0.f;
        s_ctot[tid] = 0.f;
        s_cpos[tid] = 0.f;
        s_labA[tid] = labels[r0 + tid];
        s_labB[tid] = labels[c0 + tid];
    }

    f32x4 acc[4][4];
    #pragma unroll
    for (int m = 0; m < 4; ++m)
        #pragma unroll
        for (int n = 0; n < 4; ++n)
            acc[m][n] = f32x4{0.f, 0.f, 0.f, 0.f};

    for (int kt = 0; kt < DIM / BK; ++kt) {
        __syncthreads();   // LDS reuse safety + (kt==0) init visibility
        const int k0 = kt * BK;
        #pragma unroll
        for (int it = 0; it < 4; ++it) {
            const int t_lin = it * 256 + tid;          // 0..1023 chunk id (16B chunks)
            const int r   = t_lin >> 3;                // row 0..127
            const int cc8 = (t_lin & 7) * 8;           // col element 0,8,..,56
            const unsigned short* srcA = e + (size_t)(r0 + r) * DIM + k0 + cc8;
            const unsigned short* srcB = e + (size_t)(c0 + r) * DIM + k0 + cc8;
            GLD_TO_LDS16(srcA, &sA[r][cc8]);
            GLD_TO_LDS16(srcB, &sB[r][cc8]);
        }
        __syncthreads();   // compiler drains vmcnt before the barrier

        #pragma unroll
        for (int ks = 0; ks < BK / 32; ++ks) {
            const int kb = ks * 32 + hi * 8;
            short8 a[4], b[4];
            #pragma unroll
            for (int m = 0; m < 4; ++m)
                a[m] = *reinterpret_cast<const short8*>(&sA[wr * 64 + m * 16 + lo][kb]);
            #pragma unroll
            for (int n = 0; n < 4; ++n)
                b[n] = *reinterpret_cast<const short8*>(&sB[wc * 64 + n * 16 + lo][kb]);
            #pragma unroll
            for (int m = 0; m < 4; ++m)
                #pragma unroll
                for (int n = 0; n < 4; ++n)
                    acc[m][n] = __builtin_amdgcn_mfma_f32_16x16x32_bf16(a[m], b[n], acc[m][n], 0, 0, 0);
        }
    }

    // ---------------- epilogue: exp + masks + row sums + col sums ----------------
    // C/D layout (m89-verified): col = n*16 + lo, row = m*16 + hi*4 + r
    float ct[4] = {0.f, 0.f, 0.f, 0.f};   // per-lane col partial (cols wc*64+n*16+lo)
    float cp[4] = {0.f, 0.f, 0.f, 0.f};
    #pragma unroll
    for (int m = 0; m < 4; ++m) {
        #pragma unroll
        for (int r = 0; r < 4; ++r) {
            const int lrow = wr * 64 + m * 16 + hi * 4 + r;
            const int grow = r0 + lrow;
            const int labr = s_labA[lrow];
            float tp = 0.f, pp = 0.f;
            #pragma unroll
            for (int n = 0; n < 4; ++n) {
                const int lcol = wc * 64 + n * 16 + lo;
                const int gcol = c0 + lcol;
                const float v = __expf(acc[m][n][r]);   // tau = 1
                const float vt = (grow == gcol) ? 0.f : v;
                const float vp = (s_labB[lcol] == labr) ? vt : 0.f;
                tp += vt;
                pp += vp;
                ct[n] += vt;
                cp[n] += vp;
            }
            #pragma unroll
            for (int off = 1; off <= 8; off <<= 1) {
                tp += __shfl_xor(tp, off);
                pp += __shfl_xor(pp, off);
            }
            if (lo == 0) {
                atomicAdd(&s_tot[lrow], tp);   // LDS atomics (ds_add_f32)
                atomicAdd(&s_pos[lrow], pp);
            }
        }
    }
    if (!diag) {
        #pragma unroll
        for (int n = 0; n < 4; ++n) {
            float t = ct[n], p = cp[n];
            t += __shfl_xor(t, 16);  t += __shfl_xor(t, 32);
            p += __shfl_xor(p, 16);  p += __shfl_xor(p, 32);
            if (hi == 0) {                       // lanes 0..15 hold col totals
                atomicAdd(&s_ctot[wc * 64 + n * 16 + lo], t);
                atomicAdd(&s_cpos[wc * 64 + n * 16 + lo], p);
            }
        }
    }
    __syncthreads();
    if (tid < BM) {
        part_tot[(size_t)bx * NROWS + r0 + tid] = s_tot[tid];
        part_pos[(size_t)bx * NROWS + r0 + tid] = s_pos[tid];
        if (!diag) {
            part_tot[(size_t)by * NROWS + c0 + tid] = s_ctot[tid];
            part_pos[(size_t)by * NROWS + c0 + tid] = s_cpos[tid];
        }
    }
}

// ---------------- Kernel 3: per-row loss, one wave per 64 rows ----------------
__global__ __launch_bounds__(64) void rowloss_kernel(
        const float* __restrict__ part_tot, const float* __restrict__ part_pos,
        float* __restrict__ blk_sum, float* __restrict__ blk_cnt) {
    const int tid = threadIdx.x;
    const int row = blockIdx.x * 64 + tid;
    float t = 0.f, p = 0.f;
    #pragma unroll 8
    for (int c = 0; c < NTILES; ++c) {
        t += part_tot[(size_t)c * NROWS + row];
        p += part_pos[(size_t)c * NROWS + row];
    }
    float li = 0.f, vc = 0.f;
    if (p > 0.f) { li = logf(t) - logf(p); vc = 1.f; }
    #pragma unroll
    for (int off = 32; off; off >>= 1) {
        li += __shfl_xor(li, off);
        vc += __shfl_xor(vc, off);
    }
    if (tid == 0) {
        blk_sum[blockIdx.x] = li;
        blk_cnt[blockIdx.x] = vc;
    }
}

// ---------------- Kernel 4: final reduce, one wave ----------------
__global__ __launch_bounds__(64) void final_kernel(const float* __restrict__ blk_sum,
                                                   const float* __restrict__ blk_cnt,
                                                   float* __restrict__ out) {
    const int tid = threadIdx.x;           // 64 threads, 128 partials
    float s = blk_sum[tid] + blk_sum[tid + 64];
    float c = blk_cnt[tid] + blk_cnt[tid + 64];
    #pragma unroll
    for (int off = 32; off; off >>= 1) {
        s += __shfl_xor(s, off);
        c += __shfl_xor(c, off);
    }
    if (tid == 0) out[0] = (c > 0.f) ? s / c : 0.f;
}

// ---------------- host ----------------
extern "C" void kernel_launch(void* const* d_in, const int* in_sizes, int n_in,
                              void* d_out, int out_size, void* d_ws, size_t ws_size,
                              hipStream_t stream) {
    const float* embs  = (const float*)d_in[0];
    const int* labels  = (const int*)d_in[1];
    float* out         = (float*)d_out;

    // workspace layout
    unsigned short* e = (unsigned short*)d_ws;                       // 8 MB bf16 normalized
    size_t off = (size_t)NROWS * DIM * sizeof(unsigned short);       // 8388608
    float* part_tot = (float*)((char*)d_ws + off);  off += (size_t)NTILES * NROWS * sizeof(float);
    float* part_pos = (float*)((char*)d_ws + off);  off += (size_t)NTILES * NROWS * sizeof(float);
    float* blk_sum  = (float*)((char*)d_ws + off);  off += 128 * sizeof(float);
    float* blk_cnt  = (float*)((char*)d_ws + off);

    normalize_kernel<<<NROWS, 256, 0, stream>>>(embs, e);
    sim_kernel<<<dim3(NTILES, NTILES), 256, 0, stream>>>(e, labels, part_tot, part_pos);
    rowloss_kernel<<<NROWS / 64, 64, 0, stream>>>(part_tot, part_pos, blk_sum, blk_cnt);
    final_kernel<<<1, 64, 0, stream>>>(blk_sum, blk_cnt, out);
}

// Round 13
// 163.732 us; speedup vs baseline: 1.2885x; 1.1409x over previous
//
#include <hip/hip_runtime.h>
#include <hip/hip_bf16.h>

#define NROWS 8192
#define DIM 512
#define BM 128
#define BN 128
#define BK 64
#define NTILES (NROWS / BM)                 // 64
#define NT_TRI (NTILES * (NTILES + 1) / 2)  // 2080 active blocks

using short8 = __attribute__((ext_vector_type(8))) short;
using f32x4  = __attribute__((ext_vector_type(4))) float;

static __device__ __forceinline__ unsigned short f2bf(float f) {
    unsigned int u = __float_as_uint(f);
    u += 0x7fffu + ((u >> 16) & 1u);   // RNE
    return (unsigned short)(u >> 16);
}

#define GLD_TO_LDS16(gsrc, ldst)                                                   \
    __builtin_amdgcn_global_load_lds(                                              \
        (const __attribute__((address_space(1))) void*)(gsrc),                     \
        (__attribute__((address_space(3))) void*)(ldst), 16, 0, 0)

// ---------------- Kernel 1: L2-normalize rows, fp32 -> bf16 ----------------
__global__ __launch_bounds__(256) void normalize_kernel(
        const float* __restrict__ embs, unsigned short* __restrict__ e) {
    const int row = blockIdx.x;
    const int tid = threadIdx.x;
    const float2 v = reinterpret_cast<const float2*>(embs + (size_t)row * DIM)[tid];
    float ss = v.x * v.x + v.y * v.y;
    #pragma unroll
    for (int off = 32; off; off >>= 1) ss += __shfl_xor(ss, off);
    __shared__ float s[4];
    if ((tid & 63) == 0) s[tid >> 6] = ss;
    __syncthreads();
    const float tot = s[0] + s[1] + s[2] + s[3];
    const float rn = rsqrtf(tot);
    ushort2 o;
    o.x = f2bf(v.x * rn);
    o.y = f2bf(v.y * rn);
    reinterpret_cast<ushort2*>(e + (size_t)row * DIM)[tid] = o;
}

// ---------------- Kernel 2: fused sim GEMM + exp + masked row/col sums --------
// Flat triangular grid: linear block t in [0, 2080) decodes to (bx >= by).
// Kills the mod-64 dispatch resonance of the 2D triangular grid (round 8:
// every round-robin slot got a constant bx, so bx=63 slots did 16x the work).
//   rows r0 = by*128 (A-strip), cols c0 = bx*128 (B-strip).
//   Row-sums -> part[bx][r0..+127]; Col-sums -> part[by][c0..+127] (bx!=by).
// Exclusive slots, every slot written once per launch -> no global atomics.
__global__ __launch_bounds__(256) void sim_kernel(
        const unsigned short* __restrict__ e, const int* __restrict__ labels,
        float* __restrict__ part_tot, float* __restrict__ part_pos) {
    // triangular decode: t = bx*(bx+1)/2 + by, by <= bx
    const int t = blockIdx.x;
    int bx = (int)((sqrtf(8.0f * (float)t + 1.0f) - 1.0f) * 0.5f);
    if ((bx + 1) * (bx + 2) / 2 <= t) ++bx;      // integer correction
    if (bx * (bx + 1) / 2 > t) --bx;
    const int by = t - bx * (bx + 1) / 2;
    const bool diag = (bx == by);

    __shared__ __align__(128) unsigned short sA[BM][BK];
    __shared__ __align__(128) unsigned short sB[BN][BK];
    __shared__ float s_tot[BM], s_pos[BM];
    __shared__ float s_ctot[BN], s_cpos[BN];
    __shared__ int s_labA[BM], s_labB[BN];

    const int tid  = threadIdx.x;
    const int lane = tid & 63;
    const int wv   = tid >> 6;
    const int wr   = wv >> 1;           // wave row in 2x2 grid
    const int wc   = wv & 1;            // wave col
    const int lo   = lane & 15;
    const int hi   = lane >> 4;

    const int c0 = bx * BN;
    const int r0 = by * BM;

    if (tid < BM) {
        s_tot[tid] = 0.f;
        s_pos[tid] = 0.f;
        s_ctot[tid] = 0.f;
        s_cpos[tid] = 0.f;
        s_labA[tid] = labels[r0 + tid];
        s_labB[tid] = labels[c0 + tid];
    }

    f32x4 acc[4][4];
    #pragma unroll
    for (int m = 0; m < 4; ++m)
        #pragma unroll
        for (int n = 0; n < 4; ++n)
            acc[m][n] = f32x4{0.f, 0.f, 0.f, 0.f};

    for (int kt = 0; kt < DIM / BK; ++kt) {
        __syncthreads();   // LDS reuse safety + (kt==0) init visibility
        const int k0 = kt * BK;
        #pragma unroll
        for (int it = 0; it < 4; ++it) {
            const int t_lin = it * 256 + tid;          // 0..1023 chunk id (16B chunks)
            const int r   = t_lin >> 3;                // row 0..127
            const int cc8 = (t_lin & 7) * 8;           // col element 0,8,..,56
            const unsigned short* srcA = e + (size_t)(r0 + r) * DIM + k0 + cc8;
            const unsigned short* srcB = e + (size_t)(c0 + r) * DIM + k0 + cc8;
            GLD_TO_LDS16(srcA, &sA[r][cc8]);
            GLD_TO_LDS16(srcB, &sB[r][cc8]);
        }
        __syncthreads();   // compiler drains vmcnt before the barrier

        #pragma unroll
        for (int ks = 0; ks < BK / 32; ++ks) {
            const int kb = ks * 32 + hi * 8;
            short8 a[4], b[4];
            #pragma unroll
            for (int m = 0; m < 4; ++m)
                a[m] = *reinterpret_cast<const short8*>(&sA[wr * 64 + m * 16 + lo][kb]);
            #pragma unroll
            for (int n = 0; n < 4; ++n)
                b[n] = *reinterpret_cast<const short8*>(&sB[wc * 64 + n * 16 + lo][kb]);
            #pragma unroll
            for (int m = 0; m < 4; ++m)
                #pragma unroll
                for (int n = 0; n < 4; ++n)
                    acc[m][n] = __builtin_amdgcn_mfma_f32_16x16x32_bf16(a[m], b[n], acc[m][n], 0, 0, 0);
        }
    }

    // ---------------- epilogue: exp + masks + row sums + col sums ----------------
    // C/D layout (m89-verified): col = n*16 + lo, row = m*16 + hi*4 + r
    float ct[4] = {0.f, 0.f, 0.f, 0.f};   // per-lane col partial (cols wc*64+n*16+lo)
    float cp[4] = {0.f, 0.f, 0.f, 0.f};
    #pragma unroll
    for (int m = 0; m < 4; ++m) {
        #pragma unroll
        for (int r = 0; r < 4; ++r) {
            const int lrow = wr * 64 + m * 16 + hi * 4 + r;
            const int grow = r0 + lrow;
            const int labr = s_labA[lrow];
            float tp = 0.f, pp = 0.f;
            #pragma unroll
            for (int n = 0; n < 4; ++n) {
                const int lcol = wc * 64 + n * 16 + lo;
                const int gcol = c0 + lcol;
                const float v = __expf(acc[m][n][r]);   // tau = 1
                const float vt = (grow == gcol) ? 0.f : v;
                const float vp = (s_labB[lcol] == labr) ? vt : 0.f;
                tp += vt;
                pp += vp;
                ct[n] += vt;
                cp[n] += vp;
            }
            #pragma unroll
            for (int off = 1; off <= 8; off <<= 1) {
                tp += __shfl_xor(tp, off);
                pp += __shfl_xor(pp, off);
            }
            if (lo == 0) {
                atomicAdd(&s_tot[lrow], tp);   // LDS atomics (ds_add_f32)
                atomicAdd(&s_pos[lrow], pp);
            }
        }
    }
    if (!diag) {
        #pragma unroll
        for (int n = 0; n < 4; ++n) {
            float t2 = ct[n], p2 = cp[n];
            t2 += __shfl_xor(t2, 16);  t2 += __shfl_xor(t2, 32);
            p2 += __shfl_xor(p2, 16);  p2 += __shfl_xor(p2, 32);
            if (hi == 0) {                       // lanes 0..15 hold col totals
                atomicAdd(&s_ctot[wc * 64 + n * 16 + lo], t2);
                atomicAdd(&s_cpos[wc * 64 + n * 16 + lo], p2);
            }
        }
    }
    __syncthreads();
    if (tid < BM) {
        part_tot[(size_t)bx * NROWS + r0 + tid] = s_tot[tid];
        part_pos[(size_t)bx * NROWS + r0 + tid] = s_pos[tid];
        if (!diag) {
            part_tot[(size_t)by * NROWS + c0 + tid] = s_ctot[tid];
            part_pos[(size_t)by * NROWS + c0 + tid] = s_cpos[tid];
        }
    }
}

// ---------------- Kernel 3: per-row loss, 4 threads per row ----------------
// 128 blocks x 256 threads = 512 waves (4x round 8's parallelism).
__global__ __launch_bounds__(256) void rowloss_kernel(
        const float* __restrict__ part_tot, const float* __restrict__ part_pos,
        float* __restrict__ blk_sum, float* __restrict__ blk_cnt) {
    const int tid = threadIdx.x;
    const int sub = tid & 3;                        // slice quarter
    const int row = blockIdx.x * 64 + (tid >> 2);   // 64 rows per block
    float t = 0.f, p = 0.f;
    #pragma unroll
    for (int c = sub; c < NTILES; c += 4) {         // 16 loads per array
        t += part_tot[(size_t)c * NROWS + row];
        p += part_pos[(size_t)c * NROWS + row];
    }
    t += __shfl_xor(t, 1);  t += __shfl_xor(t, 2);  // combine 4-lane group
    p += __shfl_xor(p, 1);  p += __shfl_xor(p, 2);
    float li = 0.f, vc = 0.f;
    if (sub == 0 && p > 0.f) { li = logf(t) - logf(p); vc = 1.f; }
    // li/vc nonzero only at sub==0 lanes; xor offsets >=4 stay within sub class
    #pragma unroll
    for (int off = 4; off < 64; off <<= 1) {
        li += __shfl_xor(li, off);
        vc += __shfl_xor(vc, off);
    }
    __shared__ float ss[4], sc[4];
    if ((tid & 63) == 0) { ss[tid >> 6] = li; sc[tid >> 6] = vc; }
    __syncthreads();
    if (tid == 0) {
        blk_sum[blockIdx.x] = ss[0] + ss[1] + ss[2] + ss[3];
        blk_cnt[blockIdx.x] = sc[0] + sc[1] + sc[2] + sc[3];
    }
}

// ---------------- Kernel 4: final reduce, one wave ----------------
__global__ __launch_bounds__(64) void final_kernel(const float* __restrict__ blk_sum,
                                                   const float* __restrict__ blk_cnt,
                                                   float* __restrict__ out) {
    const int tid = threadIdx.x;           // 64 threads, 128 partials
    float s = blk_sum[tid] + blk_sum[tid + 64];
    float c = blk_cnt[tid] + blk_cnt[tid + 64];
    #pragma unroll
    for (int off = 32; off; off >>= 1) {
        s += __shfl_xor(s, off);
        c += __shfl_xor(c, off);
    }
    if (tid == 0) out[0] = (c > 0.f) ? s / c : 0.f;
}

// ---------------- host ----------------
extern "C" void kernel_launch(void* const* d_in, const int* in_sizes, int n_in,
                              void* d_out, int out_size, void* d_ws, size_t ws_size,
                              hipStream_t stream) {
    const float* embs  = (const float*)d_in[0];
    const int* labels  = (const int*)d_in[1];
    float* out         = (float*)d_out;

    // workspace layout
    unsigned short* e = (unsigned short*)d_ws;                       // 8 MB bf16 normalized
    size_t off = (size_t)NROWS * DIM * sizeof(unsigned short);       // 8388608
    float* part_tot = (float*)((char*)d_ws + off);  off += (size_t)NTILES * NROWS * sizeof(float);
    float* part_pos = (float*)((char*)d_ws + off);  off += (size_t)NTILES * NROWS * sizeof(float);
    float* blk_sum  = (float*)((char*)d_ws + off);  off += 128 * sizeof(float);
    float* blk_cnt  = (float*)((char*)d_ws + off);

    normalize_kernel<<<NROWS, 256, 0, stream>>>(embs, e);
    sim_kernel<<<NT_TRI, 256, 0, stream>>>(e, labels, part_tot, part_pos);
    rowloss_kernel<<<NROWS / 64, 256, 0, stream>>>(part_tot, part_pos, blk_sum, blk_cnt);
    final_kernel<<<1, 64, 0, stream>>>(blk_sum, blk_cnt, out);
}